// Round 1
// baseline (1329.487 us; speedup 1.0000x reference)
//
#include <hip/hip_runtime.h>
#include <hip/hip_bf16.h>

// NodeModel: edge MLP ([x[col]||edge_attr] -> 64 -> 64, relu,relu) -> scatter_mean
// over row -> node MLP ([x||agg||u[batch]] -> 64 relu -> 32).
// N=50000, E=1.6M, D_IN=D_EDGE=32, D_H=64, D_U=16, D_OUT=32.
//
// Decomposition: wave-per-edge / wave-per-node. lane = output neuron.
// Weight columns live in VGPRs (persistent across the grid-stride loop);
// per-edge inputs are wave-uniform -> scalar loads; layer-2 input broadcast
// via __shfl. Scatter via native f32 atomics (unsafeAtomicAdd).

#define DH 64

__device__ __forceinline__ int uload_i(const int* p) { return __builtin_amdgcn_readfirstlane(*p); }

__global__ __launch_bounds__(256) void edge_mlp_scatter(
    const float* __restrict__ x,      // [N,32]
    const int*   __restrict__ erow,   // [E]
    const int*   __restrict__ ecol,   // [E]
    const float* __restrict__ eattr,  // [E,32]
    const float* __restrict__ W1a,    // [64,64] row-major (in,out)
    const float* __restrict__ b1a,    // [64]
    const float* __restrict__ W1b,    // [64,64]
    const float* __restrict__ b1b,    // [64]
    float* __restrict__ summed,       // [N,64]
    float* __restrict__ counts,       // [N]
    int E_)
{
    const int lane = threadIdx.x & 63;
    const int wid  = blockIdx.x * (blockDim.x >> 6) + (threadIdx.x >> 6);
    const int nw   = gridDim.x * (blockDim.x >> 6);

    // Per-lane weight columns: wa[k] = W1a[k][lane], wb[k] = W1b[k][lane]
    float wa[64], wb[64];
#pragma unroll
    for (int k = 0; k < 64; ++k) wa[k] = W1a[k * 64 + lane];
#pragma unroll
    for (int k = 0; k < 64; ++k) wb[k] = W1b[k * 64 + lane];
    const float ba = b1a[lane];
    const float bb = b1b[lane];

    for (int e = wid; e < E_; e += nw) {
        const int c = __builtin_amdgcn_readfirstlane(ecol[e]);
        const int r = __builtin_amdgcn_readfirstlane(erow[e]);
        const float* __restrict__ xp = x + (size_t)c * 32;
        const float* __restrict__ ap = eattr + (size_t)e * 32;

        // layer 1: acc = b + sum_k in[k] * W1a[k][lane]; in wave-uniform
        float acc = ba;
#pragma unroll
        for (int k = 0; k < 32; ++k) acc = fmaf(xp[k], wa[k], acc);
#pragma unroll
        for (int k = 0; k < 32; ++k) acc = fmaf(ap[k], wa[32 + k], acc);
        const float h1 = fmaxf(acc, 0.0f);

        // layer 2: broadcast h1[k] from lane k
        float acc2 = bb;
#pragma unroll
        for (int k = 0; k < 64; ++k) acc2 = fmaf(__shfl(h1, k), wb[k], acc2);
        const float h2 = fmaxf(acc2, 0.0f);

        unsafeAtomicAdd(&summed[(size_t)r * 64 + lane], h2);
        if (lane == 0) unsafeAtomicAdd(&counts[r], 1.0f);
    }
}

__global__ __launch_bounds__(256) void node_mlp(
    const float* __restrict__ x,      // [N,32]
    const float* __restrict__ summed, // [N,64]
    const float* __restrict__ counts, // [N]
    const float* __restrict__ u,      // [G,16]
    const int*   __restrict__ batch,  // [N]
    const float* __restrict__ W2a,    // [112,64]
    const float* __restrict__ b2a,    // [64]
    const float* __restrict__ W2b,    // [64,32]
    const float* __restrict__ b2b,    // [32]
    float* __restrict__ out,          // [N,32]
    int N_)
{
    const int lane = threadIdx.x & 63;
    const int wid  = blockIdx.x * (blockDim.x >> 6) + (threadIdx.x >> 6);
    const int nw   = gridDim.x * (blockDim.x >> 6);

    float wa[112];                    // column `lane` of W2a
#pragma unroll
    for (int k = 0; k < 112; ++k) wa[k] = W2a[k * 64 + lane];
    const int oc = lane & 31;
    float wb[64];                     // column `oc` of W2b
#pragma unroll
    for (int k = 0; k < 64; ++k) wb[k] = W2b[k * 32 + oc];
    const float ba = b2a[lane];
    const float bbias = b2b[oc];

    for (int n = wid; n < N_; n += nw) {
        const int g = __builtin_amdgcn_readfirstlane(batch[n]);
        const float* __restrict__ xp = x + (size_t)n * 32;
        const float* __restrict__ sp = summed + (size_t)n * 64;
        const float* __restrict__ up = u + (size_t)g * 16;
        const float inv = 1.0f / fmaxf(counts[n], 1.0f);

        float acc = ba;
#pragma unroll
        for (int k = 0; k < 32; ++k) acc = fmaf(xp[k], wa[k], acc);
#pragma unroll
        for (int k = 0; k < 64; ++k) acc = fmaf(sp[k] * inv, wa[32 + k], acc);
#pragma unroll
        for (int k = 0; k < 16; ++k) acc = fmaf(up[k], wa[96 + k], acc);
        const float z = fmaxf(acc, 0.0f);

        float acc2 = bbias;
#pragma unroll
        for (int k = 0; k < 64; ++k) acc2 = fmaf(__shfl(z, k), wb[k], acc2);
        if (lane < 32) out[(size_t)n * 32 + lane] = acc2;
    }
}

extern "C" void kernel_launch(void* const* d_in, const int* in_sizes, int n_in,
                              void* d_out, int out_size, void* d_ws, size_t ws_size,
                              hipStream_t stream) {
    const float* x     = (const float*)d_in[0];
    const int*   eidx  = (const int*)d_in[1];   // [2,E] int32
    const float* eattr = (const float*)d_in[2];
    const float* u     = (const float*)d_in[3];
    const int*   batch = (const int*)d_in[4];
    const float* W1a   = (const float*)d_in[5];
    const float* b1a   = (const float*)d_in[6];
    const float* W1b   = (const float*)d_in[7];
    const float* b1b   = (const float*)d_in[8];
    const float* W2a   = (const float*)d_in[9];
    const float* b2a   = (const float*)d_in[10];
    const float* W2b   = (const float*)d_in[11];
    const float* b2b   = (const float*)d_in[12];
    float* out = (float*)d_out;

    const int N = in_sizes[0] / 32;
    const int E = in_sizes[1] / 2;
    const int* erow = eidx;
    const int* ecol = eidx + E;

    float* summed = (float*)d_ws;                 // [N,64]
    float* counts = summed + (size_t)N * 64;      // [N]
    hipMemsetAsync(d_ws, 0, ((size_t)N * 64 + N) * sizeof(float), stream);

    edge_mlp_scatter<<<2048, 256, 0, stream>>>(x, erow, ecol, eattr,
                                               W1a, b1a, W1b, b1b,
                                               summed, counts, E);
    node_mlp<<<1024, 256, 0, stream>>>(x, summed, counts, u, batch,
                                       W2a, b2a, W2b, b2b, out, N);
}